// Round 4
// baseline (544.779 us; speedup 1.0000x reference)
//
#include <hip/hip_runtime.h>
#include <stdint.h>

#define DI __device__ __forceinline__

typedef __attribute__((ext_vector_type(8))) short short8;
typedef __attribute__((ext_vector_type(4))) float f32x4;

DI float bf2f(unsigned short u){ union{unsigned int i; float f;} v; v.i = ((unsigned int)u)<<16; return v.f; }
DI unsigned short f2bf(float f){ union{float f; unsigned int i;} v; v.f=f; return (unsigned short)((v.i + 0x7fffu + ((v.i>>16)&1u))>>16); }
DI float siluf(float x){ return x/(1.f + __expf(-x)); }
DI f32x4 vzero(){ f32x4 z; z[0]=0.f;z[1]=0.f;z[2]=0.f;z[3]=0.f; return z; }
DI f32x4 vsplat(float x){ f32x4 z; z[0]=x;z[1]=x;z[2]=x;z[3]=x; return z; }

// ---------------- weight prep ----------------
struct PrepArgs {
  const float* W[6];
  const float* g[6];
  unsigned short* Wt[6];
  int C[6];
};

__global__ __launch_bounds__(256) void prep_transpose(PrepArgs a){
  int m = blockIdx.z;
  int C = a.C[m];
  int nt = C >> 5;
  if ((int)blockIdx.x >= nt || (int)blockIdx.y >= nt) return;
  __shared__ float tile[32][33];
  int col = threadIdx.x & 31;
  int rr  = threadIdx.x >> 5;
  const float* W = a.W[m];
  const float* g = a.g[m];
  #pragma unroll
  for (int p=0;p<4;++p){
    int r = rr + p*8;
    int cK = blockIdx.x*32 + r;
    int dN = blockIdx.y*32 + col;
    float v = W[(size_t)cK*C + dN];
    if (g) v *= g[cK];
    tile[r][col] = v;
  }
  __syncthreads();
  unsigned short* Wt = a.Wt[m];
  #pragma unroll
  for (int p=0;p<4;++p){
    int r = rr + p*8;
    int dN = blockIdx.y*32 + r;
    int cK = blockIdx.x*32 + col;
    Wt[(size_t)dN*C + cK] = f2bf(tile[col][r]);  // Wt[d][c] = g[c]*W[c][d]
  }
}

struct ColArgs {
  const float* W[4]; const float* g[4]; const float* b[4]; const float* extra[4];
  float* ocs[4]; float* obs[4]; int C[4];
};

__global__ __launch_bounds__(256) void prep_colsum(ColArgs a){
  int j = blockIdx.y;
  int C = a.C[j];
  int d0 = blockIdx.x * 64;
  if (d0 >= C) return;
  int dl = threadIdx.x & 63;
  int g  = threadIdx.x >> 6;
  int d  = d0 + dl;
  const float* W = a.W[j]; const float* gv = a.g[j]; const float* bv = a.b[j];
  float cs = 0.f, bs = 0.f;
  for (int c = g; c < C; c += 4){
    float gc = gv[c], bc = bv[c];
    float w = W[(size_t)c*C + d];
    cs += gc*w;
    bs += bc*w;
  }
  __shared__ float rcs[4][64], rbs[4][64];
  rcs[g][dl] = cs; rbs[g][dl] = bs;
  __syncthreads();
  if (threadIdx.x < 64){
    float c0 = rcs[0][dl]+rcs[1][dl]+rcs[2][dl]+rcs[3][dl];
    float b0 = rbs[0][dl]+rbs[1][dl]+rbs[2][dl]+rbs[3][dl];
    if (a.extra[j]) b0 += a.extra[j][d];
    a.ocs[j][d] = c0;
    a.obs[j][d] = b0;
  }
}

// ---------------- shared helpers ----------------
// LDS tile layout: row-major [rows][C] bf16, XOR-swizzled at 16B-chunk granularity:
// byte(row, chunk) = row*2C + ((chunk ^ (row&7))*16)

template<int C>
DI short8 readFrag(const short* S, int rowBase, int ks, int lane){
  int row = rowBase + (lane & 15);
  int chunk = (ks*4 + ((lane>>4)&3)) ^ (lane & 7);
  return *(const short8*)((const char*)S + row*(2*C) + chunk*16);
}

// stage raw x (fp32, channel-major in global) into LDS bf16 [64 px][C] (swizzled),
// vectorized: float4 along px (16B/lane), b16 transpose-writes to LDS.
// LN stats recomputed from LDS bf16 (conflict-free b128 reads), fp32 accumulate.
template<int C>
DI void stageA_x(const float* __restrict__ xb, int strideC, short* As,
                 float* red, float* smean, float* srstd){
  int tid = threadIdx.x;
  int lane = tid & 63, w = tid >> 6;
  #pragma unroll
  for (int i=0; i<C/16; ++i){
    int ic = i >> 2, ip = i & 3;
    int c  = w*(C/4) + ic*16 + (lane & 15);
    int pq = ip*4 + (lane >> 4);
    f32x4 v = *(const f32x4*)(xb + (size_t)c*strideC + pq*4);
    #pragma unroll
    for (int j=0;j<4;++j){
      int px = pq*4 + j;
      *(unsigned short*)((char*)As + px*(2*C) + (((c>>3) ^ (px&7))*16) + (c&7)*2) = f2bf(v[j]);
    }
  }
  __syncthreads();
  {
    int px = tid & 63, g = tid >> 6;
    constexpr int PER = (C/8)/4;     // chunks per thread (4 threads per row)
    float s=0.f, q=0.f;
    #pragma unroll
    for (int k=0;k<PER;++k){
      int ch = g*PER + k;
      short8 v = *(const short8*)((const char*)As + px*(2*C) + ((ch ^ (px&7))*16));
      #pragma unroll
      for (int e=0;e<8;++e){ float f = bf2f((unsigned short)v[e]); s += f; q += f*f; }
    }
    red[g*64+px] = s; red[256+g*64+px] = q;
  }
  __syncthreads();
  if (tid < 64){
    float s=0.f, q=0.f;
    #pragma unroll
    for (int gg=0; gg<4; ++gg){ s += red[gg*64+tid]; q += red[256+gg*64+tid]; }
    float m = s*(1.f/C);
    float var = fmaxf(q*(1.f/C) - m*m, 0.f);
    smean[tid] = m;
    srstd[tid] = rsqrtf(var + 1e-5f);
  }
  __syncthreads();
}

// copy bf16 row-major [ROWS][C] from global into swizzled LDS
template<int C, int ROWS>
DI void stageCopy(const unsigned short* __restrict__ src, short* dst){
  int tid = threadIdx.x;
  constexpr int CH = C/8;
  constexpr int IT = (ROWS*CH)/256;
  #pragma unroll
  for (int it=0; it<IT; ++it){
    int i = tid + it*256;
    int row = i / CH, ch = i % CH;
    short8 v = *(const short8*)(src + (size_t)row*C + ch*8);
    *(short8*)((char*)dst + row*(2*C) + ((ch ^ (row&7))*16)) = v;
  }
}

template<int C>
DI void mfmaLoop(const short* As, const short* Bs, f32x4 acc[2][4], int lane, int wr, int wc){
  #pragma unroll
  for (int ks=0; ks<C/32; ++ks){
    short8 a0 = readFrag<C>(As, wr*32 +  0, ks, lane);
    short8 a1 = readFrag<C>(As, wr*32 + 16, ks, lane);
    short8 b0 = readFrag<C>(Bs, wc*64 +  0, ks, lane);
    short8 b1 = readFrag<C>(Bs, wc*64 + 16, ks, lane);
    short8 b2 = readFrag<C>(Bs, wc*64 + 32, ks, lane);
    short8 b3 = readFrag<C>(Bs, wc*64 + 48, ks, lane);
    acc[0][0] = __builtin_amdgcn_mfma_f32_16x16x32_bf16(a0,b0,acc[0][0],0,0,0);
    acc[0][1] = __builtin_amdgcn_mfma_f32_16x16x32_bf16(a0,b1,acc[0][1],0,0,0);
    acc[0][2] = __builtin_amdgcn_mfma_f32_16x16x32_bf16(a0,b2,acc[0][2],0,0,0);
    acc[0][3] = __builtin_amdgcn_mfma_f32_16x16x32_bf16(a0,b3,acc[0][3],0,0,0);
    acc[1][0] = __builtin_amdgcn_mfma_f32_16x16x32_bf16(a1,b0,acc[1][0],0,0,0);
    acc[1][1] = __builtin_amdgcn_mfma_f32_16x16x32_bf16(a1,b1,acc[1][1],0,0,0);
    acc[1][2] = __builtin_amdgcn_mfma_f32_16x16x32_bf16(a1,b2,acc[1][2],0,0,0);
    acc[1][3] = __builtin_amdgcn_mfma_f32_16x16x32_bf16(a1,b3,acc[1][3],0,0,0);
  }
}

// ---------------- fully fused branch kernel ----------------
// Per block: 64 pixels. Phase 0: cur GEMM -> P,cur fragments in registers.
// Then for each of the 4 ref frames: stage x_t, ref GEMM, h -> LDS, conv GEMM,
// pool accumulate in registers. Finally pool -> transposed coalesced store.
// No P/CT/H global round-trips.
template<int C, int MINW>
__global__ __launch_bounds__(256, MINW) void fused_branch(
    const float* __restrict__ x,
    const unsigned short* __restrict__ WtCur,
    const unsigned short* __restrict__ WtRef,
    const unsigned short* __restrict__ WtConv,
    const float* __restrict__ colC, const float* __restrict__ biasC,
    const float* __restrict__ colR, const float* __restrict__ biasR,
    const float* __restrict__ bns, const float* __restrict__ bnb,
    float* __restrict__ out, int HW){
  constexpr int T = 5;
  constexpr int NH = C/128;
  // LDS: As(128C bytes) | Hs(128C) | Bs(256C); pool reuses the whole region
  __shared__ __align__(16) char Lraw[512*C];
  short* As = (short*)Lraw;
  short* Hs = (short*)(Lraw + 128*C);
  short* Bs = (short*)(Lraw + 256*C);
  float* pool = (float*)Lraw;
  __shared__ float red[512];
  __shared__ float smean[64], srstd[64];

  int px0 = blockIdx.x*64;
  int b = px0 / HW, hw0 = px0 % HW;
  int tid = threadIdx.x, lane = tid&63, wid = tid>>6, wr = wid>>1, wc = wid&1, hi = lane>>4;

  float csR[NH*4], biR[NH*4], scv[NH*4], sbv[NH*4];
  #pragma unroll
  for (int h=0;h<NH;++h)
    #pragma unroll
    for (int k=0;k<4;++k){
      int d = h*128 + wc*64 + k*16 + (lane&15);
      csR[h*4+k] = colR[d]; biR[h*4+k] = biasR[d];
      scv[h*4+k] = bns[d];  sbv[h*4+k] = bnb[d];
    }

  short8 pv[NH*4], cv[NH*4];
  f32x4 mx[2][NH*4], sm[2][NH*4];
  #pragma unroll
  for (int i=0;i<2;++i)
    #pragma unroll
    for (int j=0;j<NH*4;++j){ mx[i][j] = vsplat(-3.0e38f); sm[i][j] = vzero(); }

  // ---- phase 0: cur projection, results stay in registers ----
  stageA_x<C>(x + ((size_t)b*C*T + (T-1))*HW + hw0, T*HW, As, red, smean, srstd);
  #pragma unroll
  for (int h=0;h<NH;++h){
    stageCopy<C,128>(WtCur + (size_t)h*128*C, Bs);
    __syncthreads();
    f32x4 acc[2][4];
    #pragma unroll
    for (int i=0;i<2;++i)
      #pragma unroll
      for (int j=0;j<4;++j) acc[i][j] = vzero();
    mfmaLoop<C>(As, Bs, acc, lane, wr, wc);
    #pragma unroll
    for (int k=0;k<4;++k){
      int dg = h*128 + wc*64 + k*16 + (lane&15);
      float cs = colC[dg], bi = biasC[dg];
      short8 p8, c8;
      #pragma unroll
      for (int mf=0;mf<2;++mf)
        #pragma unroll
        for (int r=0;r<4;++r){
          int pl = wr*32 + mf*16 + hi*4 + r;
          float P = srstd[pl]*(acc[mf][k][r] - smean[pl]*cs) + bi;
          p8[mf*4+r] = (short)f2bf(P);
          c8[mf*4+r] = (short)*(const unsigned short*)((const char*)As + pl*(2*C) + (((dg>>3)^(pl&7))*16) + (dg&7)*2);
        }
      pv[h*4+k] = p8; cv[h*4+k] = c8;
    }
    __syncthreads();
  }

  // ---- t loop: ref GEMM -> h -> conv GEMM -> pool ----
  for (int t=0;t<4;++t){
    stageA_x<C>(x + ((size_t)b*C*T + t)*HW + hw0, T*HW, As, red, smean, srstd);
    #pragma unroll
    for (int h=0;h<NH;++h){
      stageCopy<C,128>(WtRef + (size_t)h*128*C, Bs);
      __syncthreads();
      f32x4 acc[2][4];
      #pragma unroll
      for (int i=0;i<2;++i)
        #pragma unroll
        for (int j=0;j<4;++j) acc[i][j] = vzero();
      mfmaLoop<C>(As, Bs, acc, lane, wr, wc);
      #pragma unroll
      for (int k=0;k<4;++k){
        int dg = h*128 + wc*64 + k*16 + (lane&15);
        #pragma unroll
        for (int mf=0;mf<2;++mf)
          #pragma unroll
          for (int r=0;r<4;++r){
            int pl = wr*32 + mf*16 + hi*4 + r;
            float pre = srstd[pl]*(acc[mf][k][r] - smean[pl]*csR[h*4+k]) + biR[h*4+k] + bf2f((unsigned short)pv[h*4+k][mf*4+r]);
            float hv = bf2f((unsigned short)cv[h*4+k][mf*4+r]) + siluf(pre);
            *(unsigned short*)((char*)Hs + pl*(2*C) + (((dg>>3)^(pl&7))*16) + (dg&7)*2) = f2bf(hv);
          }
      }
      __syncthreads();
    }
    #pragma unroll
    for (int h=0;h<NH;++h){
      stageCopy<C,128>(WtConv + (size_t)h*128*C, Bs);
      __syncthreads();
      f32x4 acc[2][4];
      #pragma unroll
      for (int i=0;i<2;++i)
        #pragma unroll
        for (int j=0;j<4;++j) acc[i][j] = vzero();
      mfmaLoop<C>(Hs, Bs, acc, lane, wr, wc);
      #pragma unroll
      for (int k=0;k<4;++k){
        float s_ = scv[h*4+k], b_ = sbv[h*4+k];
        #pragma unroll
        for (int mf=0;mf<2;++mf)
          #pragma unroll
          for (int r=0;r<4;++r){
            float y = siluf(acc[mf][k][r]*s_ + b_);
            mx[mf][h*4+k][r] = fmaxf(mx[mf][h*4+k][r], y);
            sm[mf][h*4+k][r] += y;
          }
      }
      __syncthreads();
    }
  }

  // ---- pool -> LDS (stride C+1) -> coalesced transposed store ----
  #pragma unroll
  for (int h=0;h<NH;++h)
    #pragma unroll
    for (int k=0;k<4;++k){
      int dl = h*128 + wc*64 + k*16 + (lane&15);
      #pragma unroll
      for (int mf=0;mf<2;++mf)
        #pragma unroll
        for (int r=0;r<4;++r){
          int pl = wr*32 + mf*16 + hi*4 + r;
          pool[pl*(C+1) + dl] = mx[mf][h*4+k][r] + 0.25f*sm[mf][h*4+k][r];
        }
    }
  __syncthreads();
  #pragma unroll
  for (int it=0; it<C/16; ++it){
    int i = tid + it*256;
    int dl = i >> 4;
    int pq = (i & 15) * 4;
    f32x4 vv;
    #pragma unroll
    for (int k=0;k<4;++k) vv[k] = pool[(pq+k)*(C+1) + dl];
    *(f32x4*)(out + (size_t)(b*C + dl)*HW + hw0 + pq) = vv;
  }
}

// ---------------- host ----------------
extern "C" void kernel_launch(void* const* d_in, const int* in_sizes, int n_in,
                              void* d_out, int out_size, void* d_ws, size_t ws_size,
                              hipStream_t stream) {
  (void)in_sizes; (void)n_in; (void)out_size; (void)ws_size;
  const float* x2    = (const float*)d_in[0];
  const float* x1    = (const float*)d_in[1];
  const float* g2c   = (const float*)d_in[3];
  const float* b2c   = (const float*)d_in[4];
  const float* g2r   = (const float*)d_in[5];
  const float* b2r   = (const float*)d_in[6];
  const float* W2cur = (const float*)d_in[7];
  const float* W2ref = (const float*)d_in[8];
  const float* bias2 = (const float*)d_in[9];
  const float* convw2= (const float*)d_in[10];
  const float* bns2  = (const float*)d_in[11];
  const float* bnb2  = (const float*)d_in[12];
  const float* g1c   = (const float*)d_in[13];
  const float* b1c   = (const float*)d_in[14];
  const float* g1r   = (const float*)d_in[15];
  const float* b1r   = (const float*)d_in[16];
  const float* W1cur = (const float*)d_in[17];
  const float* W1ref = (const float*)d_in[18];
  const float* bias1 = (const float*)d_in[19];
  const float* convw1= (const float*)d_in[20];
  const float* bns1  = (const float*)d_in[21];
  const float* bnb1  = (const float*)d_in[22];

  const int C2 = 128, C1 = 256;
  const int NP2 = 8*64*64, NP1 = 8*32*32;
  const int HW2 = 4096, HW1 = 1024;

  char* ws = (char*)d_ws;
  size_t off = 0;
  auto alloc = [&](size_t bytes){ size_t o = off; off = (off + bytes + 255) & ~(size_t)255; return o; };
  size_t oWtC2 = alloc((size_t)C2*C2*2), oWtR2 = alloc((size_t)C2*C2*2), oWtV2 = alloc((size_t)C2*C2*2);
  size_t oWtC1 = alloc((size_t)C1*C1*2), oWtR1 = alloc((size_t)C1*C1*2), oWtV1 = alloc((size_t)C1*C1*2);
  size_t oColC2 = alloc(C2*4), oBiasC2 = alloc(C2*4), oColR2 = alloc(C2*4), oBiasR2 = alloc(C2*4);
  size_t oColC1 = alloc(C1*4), oBiasC1 = alloc(C1*4), oColR1 = alloc(C1*4), oBiasR1 = alloc(C1*4);

  unsigned short* WtC2 = (unsigned short*)(ws + oWtC2);
  unsigned short* WtR2 = (unsigned short*)(ws + oWtR2);
  unsigned short* WtV2 = (unsigned short*)(ws + oWtV2);
  unsigned short* WtC1 = (unsigned short*)(ws + oWtC1);
  unsigned short* WtR1 = (unsigned short*)(ws + oWtR1);
  unsigned short* WtV1 = (unsigned short*)(ws + oWtV1);
  float* ColC2 = (float*)(ws + oColC2); float* BiasC2 = (float*)(ws + oBiasC2);
  float* ColR2 = (float*)(ws + oColR2); float* BiasR2 = (float*)(ws + oBiasR2);
  float* ColC1 = (float*)(ws + oColC1); float* BiasC1 = (float*)(ws + oBiasC1);
  float* ColR1 = (float*)(ws + oColR1); float* BiasR1 = (float*)(ws + oBiasR1);

  PrepArgs pa;
  pa.W[0]=W2cur;  pa.g[0]=g2c;     pa.Wt[0]=WtC2; pa.C[0]=C2;
  pa.W[1]=W2ref;  pa.g[1]=g2r;     pa.Wt[1]=WtR2; pa.C[1]=C2;
  pa.W[2]=convw2; pa.g[2]=nullptr; pa.Wt[2]=WtV2; pa.C[2]=C2;
  pa.W[3]=W1cur;  pa.g[3]=g1c;     pa.Wt[3]=WtC1; pa.C[3]=C1;
  pa.W[4]=W1ref;  pa.g[4]=g1r;     pa.Wt[4]=WtR1; pa.C[4]=C1;
  pa.W[5]=convw1; pa.g[5]=nullptr; pa.Wt[5]=WtV1; pa.C[5]=C1;
  prep_transpose<<<dim3(8,8,6), 256, 0, stream>>>(pa);

  ColArgs ca;
  ca.W[0]=W2cur; ca.g[0]=g2c; ca.b[0]=b2c; ca.extra[0]=nullptr; ca.ocs[0]=ColC2; ca.obs[0]=BiasC2; ca.C[0]=C2;
  ca.W[1]=W2ref; ca.g[1]=g2r; ca.b[1]=b2r; ca.extra[1]=bias2;   ca.ocs[1]=ColR2; ca.obs[1]=BiasR2; ca.C[1]=C2;
  ca.W[2]=W1cur; ca.g[2]=g1c; ca.b[2]=b1c; ca.extra[2]=nullptr; ca.ocs[2]=ColC1; ca.obs[2]=BiasC1; ca.C[2]=C1;
  ca.W[3]=W1ref; ca.g[3]=g1r; ca.b[3]=b1r; ca.extra[3]=bias1;   ca.ocs[3]=ColR1; ca.obs[3]=BiasR1; ca.C[3]=C1;
  prep_colsum<<<dim3(4, 4), 256, 0, stream>>>(ca);

  float* out2 = (float*)d_out;
  float* out1 = out2 + (size_t)8*C2*HW2;

  fused_branch<128,2><<<NP2/64, 256, 0, stream>>>(
      x2, WtC2, WtR2, WtV2, ColC2, BiasC2, ColR2, BiasR2, bns2, bnb2, out2, HW2);
  fused_branch<256,1><<<NP1/64, 256, 0, stream>>>(
      x1, WtC1, WtR1, WtV1, ColC1, BiasC1, ColR1, BiasR1, bns1, bnb1, out1, HW1);
}

// Round 5
// 422.365 us; speedup vs baseline: 1.2898x; 1.2898x over previous
//
#include <hip/hip_runtime.h>
#include <stdint.h>

#define DI __device__ __forceinline__

typedef __attribute__((ext_vector_type(8))) short short8;
typedef __attribute__((ext_vector_type(4))) float f32x4;

DI float bf2f(unsigned short u){ union{unsigned int i; float f;} v; v.i = ((unsigned int)u)<<16; return v.f; }
DI unsigned short f2bf(float f){ union{float f; unsigned int i;} v; v.f=f; return (unsigned short)((v.i + 0x7fffu + ((v.i>>16)&1u))>>16); }
DI float siluf(float x){ return x/(1.f + __expf(-x)); }
DI f32x4 vzero(){ f32x4 z; z[0]=0.f;z[1]=0.f;z[2]=0.f;z[3]=0.f; return z; }
DI f32x4 vsplat(float x){ f32x4 z; z[0]=x;z[1]=x;z[2]=x;z[3]=x; return z; }

// ---------------- weight prep ----------------
struct PrepArgs {
  const float* W[6];
  const float* g[6];
  unsigned short* Wt[6];
  int C[6];
};

__global__ __launch_bounds__(256) void prep_transpose(PrepArgs a){
  int m = blockIdx.z;
  int C = a.C[m];
  int nt = C >> 5;
  if ((int)blockIdx.x >= nt || (int)blockIdx.y >= nt) return;
  __shared__ float tile[32][33];
  int col = threadIdx.x & 31;
  int rr  = threadIdx.x >> 5;
  const float* W = a.W[m];
  const float* g = a.g[m];
  #pragma unroll
  for (int p=0;p<4;++p){
    int r = rr + p*8;
    int cK = blockIdx.x*32 + r;
    int dN = blockIdx.y*32 + col;
    float v = W[(size_t)cK*C + dN];
    if (g) v *= g[cK];
    tile[r][col] = v;
  }
  __syncthreads();
  unsigned short* Wt = a.Wt[m];
  #pragma unroll
  for (int p=0;p<4;++p){
    int r = rr + p*8;
    int dN = blockIdx.y*32 + r;
    int cK = blockIdx.x*32 + col;
    Wt[(size_t)dN*C + cK] = f2bf(tile[col][r]);  // Wt[d][c] = g[c]*W[c][d]
  }
}

struct ColArgs {
  const float* W[4]; const float* g[4]; const float* b[4]; const float* extra[4];
  float* ocs[4]; float* obs[4]; int C[4];
};

__global__ __launch_bounds__(256) void prep_colsum(ColArgs a){
  int j = blockIdx.y;
  int C = a.C[j];
  int d0 = blockIdx.x * 64;
  if (d0 >= C) return;
  int dl = threadIdx.x & 63;
  int g  = threadIdx.x >> 6;
  int d  = d0 + dl;
  const float* W = a.W[j]; const float* gv = a.g[j]; const float* bv = a.b[j];
  float cs = 0.f, bs = 0.f;
  for (int c = g; c < C; c += 4){
    float gc = gv[c], bc = bv[c];
    float w = W[(size_t)c*C + d];
    cs += gc*w;
    bs += bc*w;
  }
  __shared__ float rcs[4][64], rbs[4][64];
  rcs[g][dl] = cs; rbs[g][dl] = bs;
  __syncthreads();
  if (threadIdx.x < 64){
    float c0 = rcs[0][dl]+rcs[1][dl]+rcs[2][dl]+rcs[3][dl];
    float b0 = rbs[0][dl]+rbs[1][dl]+rbs[2][dl]+rbs[3][dl];
    if (a.extra[j]) b0 += a.extra[j][d];
    a.ocs[j][d] = c0;
    a.obs[j][d] = b0;
  }
}

// ---------------- shared helpers ----------------
// LDS tile layout: row-major [rows][C] bf16, XOR-swizzled at 16B-chunk granularity:
// byte(row, chunk) = row*2C + ((chunk ^ (row&7))*16)

template<int C>
DI short8 readFrag(const short* S, int rowBase, int ks, int lane){
  int row = rowBase + (lane & 15);
  int chunk = (ks*4 + ((lane>>4)&3)) ^ (lane & 7);
  return *(const short8*)((const char*)S + row*(2*C) + chunk*16);
}

// waves 0-3 (tid256 = tid in [0,256)): write raw x (fp32 ch-major) into swizzled bf16 As
template<int C>
DI void stageX_write(const float* __restrict__ xb, int strideC, short* As, int tid256){
  int lane = tid256 & 63, w = tid256 >> 6;    // w in 0..3
  #pragma unroll
  for (int i=0; i<C/16; ++i){
    int ic = i >> 2, ip = i & 3;
    int c  = w*(C/4) + ic*16 + (lane & 15);
    int pq = ip*4 + (lane >> 4);
    f32x4 v = *(const f32x4*)(xb + (size_t)c*strideC + pq*4);
    #pragma unroll
    for (int j=0;j<4;++j){
      int px = pq*4 + j;
      *(unsigned short*)((char*)As + px*(2*C) + (((c>>3) ^ (px&7))*16) + (c&7)*2) = f2bf(v[j]);
    }
  }
}

// all 512 threads: LN stats from LDS bf16 (conflict-free b128 reads). 2 internal barriers.
template<int C>
DI void stageX_stats(const short* As, float* red, float* smean, float* srstd, int tid){
  int px = tid & 63, g = tid >> 6;            // g in 0..7
  constexpr int PER = C/64;                   // (C/8)/8 chunks per thread
  float s=0.f, q=0.f;
  #pragma unroll
  for (int k=0;k<PER;++k){
    int ch = g*PER + k;
    short8 v = *(const short8*)((const char*)As + px*(2*C) + ((ch ^ (px&7))*16));
    #pragma unroll
    for (int e=0;e<8;++e){ float f = bf2f((unsigned short)v[e]); s += f; q += f*f; }
  }
  red[g*64+px] = s; red[512 + g*64+px] = q;
  __syncthreads();
  if (tid < 64){
    float ss=0.f, qq=0.f;
    #pragma unroll
    for (int gg=0; gg<8; ++gg){ ss += red[gg*64+tid]; qq += red[512+gg*64+tid]; }
    float m = ss*(1.f/C);
    float var = fmaxf(qq*(1.f/C) - m*m, 0.f);
    smean[tid] = m;
    srstd[tid] = rsqrtf(var + 1e-5f);
  }
  __syncthreads();
}

// weight tile copy (128 rows x C), 256-thread variant (waves 4-7)
template<int C>
DI void stageW256(const unsigned short* __restrict__ src, short* dst, int tid256){
  constexpr int CH = C/8;
  constexpr int IT = (128*CH)/256;
  #pragma unroll
  for (int it=0; it<IT; ++it){
    int i = tid256 + it*256;
    int row = i / CH, ch = i % CH;
    short8 v = *(const short8*)(src + (size_t)row*C + ch*8);
    *(short8*)((char*)dst + row*(2*C) + ((ch ^ (row&7))*16)) = v;
  }
}

// weight tile copy (128 rows x C), all-512-thread variant
template<int C>
DI void stageW512(const unsigned short* __restrict__ src, short* dst, int tid){
  constexpr int CH = C/8;
  constexpr int IT = (128*CH)/512;
  #pragma unroll
  for (int it=0; it<IT; ++it){
    int i = tid + it*512;
    int row = i / CH, ch = i % CH;
    short8 v = *(const short8*)(src + (size_t)row*C + ch*8);
    *(short8*)((char*)dst + row*(2*C) + ((ch ^ (row&7))*16)) = v;
  }
}

// 8-wave GEMM pass: 64px x 128col, wave grid 2x4, per-wave 32x32, acc[2][2]
template<int C>
DI void mfmaPass(const short* As, const short* Bs, f32x4 acc[2][2], int lane, int wr, int wc){
  #pragma unroll
  for (int ks=0; ks<C/32; ++ks){
    short8 a0 = readFrag<C>(As, wr*32 +  0, ks, lane);
    short8 a1 = readFrag<C>(As, wr*32 + 16, ks, lane);
    short8 b0 = readFrag<C>(Bs, wc*32 +  0, ks, lane);
    short8 b1 = readFrag<C>(Bs, wc*32 + 16, ks, lane);
    acc[0][0] = __builtin_amdgcn_mfma_f32_16x16x32_bf16(a0,b0,acc[0][0],0,0,0);
    acc[0][1] = __builtin_amdgcn_mfma_f32_16x16x32_bf16(a0,b1,acc[0][1],0,0,0);
    acc[1][0] = __builtin_amdgcn_mfma_f32_16x16x32_bf16(a1,b0,acc[1][0],0,0,0);
    acc[1][1] = __builtin_amdgcn_mfma_f32_16x16x32_bf16(a1,b1,acc[1][1],0,0,0);
  }
}

// ---------------- fused branch kernel, 512 threads / 8 waves ----------------
template<int C, int MINW>
__global__ __launch_bounds__(512, MINW) void fused8(
    const float* __restrict__ x,
    const unsigned short* __restrict__ WtCur,
    const unsigned short* __restrict__ WtRef,
    const unsigned short* __restrict__ WtConv,
    const float* __restrict__ colC, const float* __restrict__ biasC,
    const float* __restrict__ colR, const float* __restrict__ biasR,
    const float* __restrict__ bns, const float* __restrict__ bnb,
    float* __restrict__ out, int HW){
  constexpr int T = 5;
  constexpr int NH = C/128;        // 128-col passes
  // LDS: As(128C bytes) | Hs(128C) | Bs(256C). pool reuses from the front.
  __shared__ __align__(16) char Lraw[512*C];
  short* As = (short*)Lraw;
  short* Hs = (short*)(Lraw + 128*C);
  short* Bs = (short*)(Lraw + 256*C);
  float* pool = (float*)Lraw;
  __shared__ float red[1024];
  __shared__ float smean[64], srstd[64];

  int px0 = blockIdx.x*64;
  int b = px0 / HW, hw0 = px0 % HW;
  int tid = threadIdx.x, lane = tid&63, wid = tid>>6;
  int wr = wid>>2, wc = wid&3, hi = lane>>4;

  const float* xbase = x + (size_t)b*C*T*HW + hw0;

  float csR[NH*2], biR[NH*2], scv[NH*2], sbv[NH*2];
  #pragma unroll
  for (int p=0;p<NH;++p)
    #pragma unroll
    for (int nf=0;nf<2;++nf){
      int d = p*128 + wc*32 + nf*16 + (lane&15);
      csR[p*2+nf] = colR[d]; biR[p*2+nf] = biasR[d];
      scv[p*2+nf] = bns[d];  sbv[p*2+nf] = bnb[d];
    }

  short8 pv[NH*2], cv[NH*2];
  f32x4 mx[NH*2][2], sm[NH*2][2];
  #pragma unroll
  for (int f=0;f<NH*2;++f)
    #pragma unroll
    for (int mf=0;mf<2;++mf){ mx[f][mf] = vsplat(-3.0e38f); sm[f][mf] = vzero(); }

  // ---- phase 0: cur projection, P and raw-cur fragments stay in registers ----
  if (wid < 4) stageX_write<C>(xbase + (size_t)(T-1)*HW, T*HW, As, tid);
  else         stageW256<C>(WtCur, Bs, tid - 256);
  __syncthreads();
  stageX_stats<C>(As, red, smean, srstd, tid);

  #pragma unroll
  for (int p=0;p<NH;++p){
    if (p>0){
      __syncthreads();
      stageW512<C>(WtCur + (size_t)p*128*C, Bs, tid);
      __syncthreads();
    }
    f32x4 acc[2][2];
    acc[0][0]=vzero(); acc[0][1]=vzero(); acc[1][0]=vzero(); acc[1][1]=vzero();
    mfmaPass<C>(As, Bs, acc, lane, wr, wc);
    #pragma unroll
    for (int nf=0;nf<2;++nf){
      int dg = p*128 + wc*32 + nf*16 + (lane&15);
      float cs = colC[dg], bi = biasC[dg];
      short8 p8, c8;
      #pragma unroll
      for (int mf=0;mf<2;++mf)
        #pragma unroll
        for (int r=0;r<4;++r){
          int pl = wr*32 + mf*16 + hi*4 + r;
          float P = srstd[pl]*(acc[mf][nf][r] - smean[pl]*cs) + bi;
          p8[mf*4+r] = (short)f2bf(P);
          c8[mf*4+r] = (short)*(const unsigned short*)((const char*)As + pl*(2*C) + (((dg>>3)^(pl&7))*16) + (dg&7)*2);
        }
      pv[p*2+nf] = p8; cv[p*2+nf] = c8;
    }
  }

  // ---- t loop: ref GEMM -> h(LDS) -> conv GEMM -> pool in registers ----
  for (int t=0;t<4;++t){
    __syncthreads();   // As/Bs free (phase0 reads or previous conv done)
    if (wid < 4) stageX_write<C>(xbase + (size_t)t*HW, T*HW, As, tid);
    else         stageW256<C>(WtRef, Bs, tid - 256);
    __syncthreads();
    stageX_stats<C>(As, red, smean, srstd, tid);

    #pragma unroll
    for (int p=0;p<NH;++p){
      if (p>0){
        __syncthreads();
        stageW512<C>(WtRef + (size_t)p*128*C, Bs, tid);
        __syncthreads();
      }
      f32x4 acc[2][2];
      acc[0][0]=vzero(); acc[0][1]=vzero(); acc[1][0]=vzero(); acc[1][1]=vzero();
      mfmaPass<C>(As, Bs, acc, lane, wr, wc);
      #pragma unroll
      for (int nf=0;nf<2;++nf){
        int dg = p*128 + wc*32 + nf*16 + (lane&15);
        #pragma unroll
        for (int mf=0;mf<2;++mf)
          #pragma unroll
          for (int r=0;r<4;++r){
            int pl = wr*32 + mf*16 + hi*4 + r;
            float pre = srstd[pl]*(acc[mf][nf][r] - smean[pl]*csR[p*2+nf]) + biR[p*2+nf]
                      + bf2f((unsigned short)pv[p*2+nf][mf*4+r]);
            float hv = bf2f((unsigned short)cv[p*2+nf][mf*4+r]) + siluf(pre);
            *(unsigned short*)((char*)Hs + pl*(2*C) + (((dg>>3)^(pl&7))*16) + (dg&7)*2) = f2bf(hv);
          }
      }
    }

    #pragma unroll
    for (int p=0;p<NH;++p){
      __syncthreads();   // Hs writes complete / Bs free
      stageW512<C>(WtConv + (size_t)p*128*C, Bs, tid);
      __syncthreads();
      f32x4 acc[2][2];
      acc[0][0]=vzero(); acc[0][1]=vzero(); acc[1][0]=vzero(); acc[1][1]=vzero();
      mfmaPass<C>(Hs, Bs, acc, lane, wr, wc);
      #pragma unroll
      for (int nf=0;nf<2;++nf){
        float s_ = scv[p*2+nf], b_ = sbv[p*2+nf];
        #pragma unroll
        for (int mf=0;mf<2;++mf)
          #pragma unroll
          for (int r=0;r<4;++r){
            float y = siluf(acc[mf][nf][r]*s_ + b_);
            mx[p*2+nf][mf][r] = fmaxf(mx[p*2+nf][mf][r], y);
            sm[p*2+nf][mf][r] += y;
          }
      }
    }
  }

  // ---- pool -> LDS (stride C+1) -> coalesced transposed store ----
  __syncthreads();
  #pragma unroll
  for (int p=0;p<NH;++p)
    #pragma unroll
    for (int nf=0;nf<2;++nf){
      int dl = p*128 + wc*32 + nf*16 + (lane&15);
      #pragma unroll
      for (int mf=0;mf<2;++mf)
        #pragma unroll
        for (int r=0;r<4;++r){
          int pl = wr*32 + mf*16 + hi*4 + r;
          pool[pl*(C+1) + dl] = mx[p*2+nf][mf][r] + 0.25f*sm[p*2+nf][mf][r];
        }
    }
  __syncthreads();
  #pragma unroll
  for (int it=0; it<C/32; ++it){
    int i = tid + it*512;
    int dl = i >> 4;
    int pq = (i & 15) * 4;
    f32x4 vv;
    #pragma unroll
    for (int k=0;k<4;++k) vv[k] = pool[(pq+k)*(C+1) + dl];
    *(f32x4*)(out + (size_t)(b*C + dl)*HW + hw0 + pq) = vv;
  }
}

// ---------------- host ----------------
extern "C" void kernel_launch(void* const* d_in, const int* in_sizes, int n_in,
                              void* d_out, int out_size, void* d_ws, size_t ws_size,
                              hipStream_t stream) {
  (void)in_sizes; (void)n_in; (void)out_size; (void)ws_size;
  const float* x2    = (const float*)d_in[0];
  const float* x1    = (const float*)d_in[1];
  const float* g2c   = (const float*)d_in[3];
  const float* b2c   = (const float*)d_in[4];
  const float* g2r   = (const float*)d_in[5];
  const float* b2r   = (const float*)d_in[6];
  const float* W2cur = (const float*)d_in[7];
  const float* W2ref = (const float*)d_in[8];
  const float* bias2 = (const float*)d_in[9];
  const float* convw2= (const float*)d_in[10];
  const float* bns2  = (const float*)d_in[11];
  const float* bnb2  = (const float*)d_in[12];
  const float* g1c   = (const float*)d_in[13];
  const float* b1c   = (const float*)d_in[14];
  const float* g1r   = (const float*)d_in[15];
  const float* b1r   = (const float*)d_in[16];
  const float* W1cur = (const float*)d_in[17];
  const float* W1ref = (const float*)d_in[18];
  const float* bias1 = (const float*)d_in[19];
  const float* convw1= (const float*)d_in[20];
  const float* bns1  = (const float*)d_in[21];
  const float* bnb1  = (const float*)d_in[22];

  const int C2 = 128, C1 = 256;
  const int NP2 = 8*64*64, NP1 = 8*32*32;
  const int HW2 = 4096, HW1 = 1024;

  char* ws = (char*)d_ws;
  size_t off = 0;
  auto alloc = [&](size_t bytes){ size_t o = off; off = (off + bytes + 255) & ~(size_t)255; return o; };
  size_t oWtC2 = alloc((size_t)C2*C2*2), oWtR2 = alloc((size_t)C2*C2*2), oWtV2 = alloc((size_t)C2*C2*2);
  size_t oWtC1 = alloc((size_t)C1*C1*2), oWtR1 = alloc((size_t)C1*C1*2), oWtV1 = alloc((size_t)C1*C1*2);
  size_t oColC2 = alloc(C2*4), oBiasC2 = alloc(C2*4), oColR2 = alloc(C2*4), oBiasR2 = alloc(C2*4);
  size_t oColC1 = alloc(C1*4), oBiasC1 = alloc(C1*4), oColR1 = alloc(C1*4), oBiasR1 = alloc(C1*4);

  unsigned short* WtC2 = (unsigned short*)(ws + oWtC2);
  unsigned short* WtR2 = (unsigned short*)(ws + oWtR2);
  unsigned short* WtV2 = (unsigned short*)(ws + oWtV2);
  unsigned short* WtC1 = (unsigned short*)(ws + oWtC1);
  unsigned short* WtR1 = (unsigned short*)(ws + oWtR1);
  unsigned short* WtV1 = (unsigned short*)(ws + oWtV1);
  float* ColC2 = (float*)(ws + oColC2); float* BiasC2 = (float*)(ws + oBiasC2);
  float* ColR2 = (float*)(ws + oColR2); float* BiasR2 = (float*)(ws + oBiasR2);
  float* ColC1 = (float*)(ws + oColC1); float* BiasC1 = (float*)(ws + oBiasC1);
  float* ColR1 = (float*)(ws + oColR1); float* BiasR1 = (float*)(ws + oBiasR1);

  PrepArgs pa;
  pa.W[0]=W2cur;  pa.g[0]=g2c;     pa.Wt[0]=WtC2; pa.C[0]=C2;
  pa.W[1]=W2ref;  pa.g[1]=g2r;     pa.Wt[1]=WtR2; pa.C[1]=C2;
  pa.W[2]=convw2; pa.g[2]=nullptr; pa.Wt[2]=WtV2; pa.C[2]=C2;
  pa.W[3]=W1cur;  pa.g[3]=g1c;     pa.Wt[3]=WtC1; pa.C[3]=C1;
  pa.W[4]=W1ref;  pa.g[4]=g1r;     pa.Wt[4]=WtR1; pa.C[4]=C1;
  pa.W[5]=convw1; pa.g[5]=nullptr; pa.Wt[5]=WtV1; pa.C[5]=C1;
  prep_transpose<<<dim3(8,8,6), 256, 0, stream>>>(pa);

  ColArgs ca;
  ca.W[0]=W2cur; ca.g[0]=g2c; ca.b[0]=b2c; ca.extra[0]=nullptr; ca.ocs[0]=ColC2; ca.obs[0]=BiasC2; ca.C[0]=C2;
  ca.W[1]=W2ref; ca.g[1]=g2r; ca.b[1]=b2r; ca.extra[1]=bias2;   ca.ocs[1]=ColR2; ca.obs[1]=BiasR2; ca.C[1]=C2;
  ca.W[2]=W1cur; ca.g[2]=g1c; ca.b[2]=b1c; ca.extra[2]=nullptr; ca.ocs[2]=ColC1; ca.obs[2]=BiasC1; ca.C[2]=C1;
  ca.W[3]=W1ref; ca.g[3]=g1r; ca.b[3]=b1r; ca.extra[3]=bias1;   ca.ocs[3]=ColR1; ca.obs[3]=BiasR1; ca.C[3]=C1;
  prep_colsum<<<dim3(4, 4), 256, 0, stream>>>(ca);

  float* out2 = (float*)d_out;
  float* out1 = out2 + (size_t)8*C2*HW2;

  fused8<128,4><<<NP2/64, 512, 0, stream>>>(
      x2, WtC2, WtR2, WtV2, ColC2, BiasC2, ColR2, BiasR2, bns2, bnb2, out2, HW2);
  fused8<256,2><<<NP1/64, 512, 0, stream>>>(
      x1, WtC1, WtR1, WtV1, ColC1, BiasC1, ColR1, BiasR1, bns1, bnb1, out1, HW1);
}

// Round 6
// 345.229 us; speedup vs baseline: 1.5780x; 1.2234x over previous
//
#include <hip/hip_runtime.h>
#include <stdint.h>

#define DI __device__ __forceinline__

typedef __attribute__((ext_vector_type(8))) short short8;
typedef __attribute__((ext_vector_type(4))) float f32x4;

DI float bf2f(unsigned short u){ union{unsigned int i; float f;} v; v.i = ((unsigned int)u)<<16; return v.f; }
DI unsigned short f2bf(float f){ union{float f; unsigned int i;} v; v.f=f; return (unsigned short)((v.i + 0x7fffu + ((v.i>>16)&1u))>>16); }
DI float siluf(float x){ return x/(1.f + __expf(-x)); }
DI f32x4 vzero(){ f32x4 z; z[0]=0.f;z[1]=0.f;z[2]=0.f;z[3]=0.f; return z; }
DI f32x4 vsplat(float x){ f32x4 z; z[0]=x;z[1]=x;z[2]=x;z[3]=x; return z; }

// ---------------- weight prep ----------------
struct PrepArgs {
  const float* W[6];
  const float* g[6];
  unsigned short* Wt[6];
  int C[6];
};

__global__ __launch_bounds__(256) void prep_transpose(PrepArgs a){
  int m = blockIdx.z;
  int C = a.C[m];
  int nt = C >> 5;
  if ((int)blockIdx.x >= nt || (int)blockIdx.y >= nt) return;
  __shared__ float tile[32][33];
  int col = threadIdx.x & 31;
  int rr  = threadIdx.x >> 5;
  const float* W = a.W[m];
  const float* g = a.g[m];
  #pragma unroll
  for (int p=0;p<4;++p){
    int r = rr + p*8;
    int cK = blockIdx.x*32 + r;
    int dN = blockIdx.y*32 + col;
    float v = W[(size_t)cK*C + dN];
    if (g) v *= g[cK];
    tile[r][col] = v;
  }
  __syncthreads();
  unsigned short* Wt = a.Wt[m];
  #pragma unroll
  for (int p=0;p<4;++p){
    int r = rr + p*8;
    int dN = blockIdx.y*32 + r;
    int cK = blockIdx.x*32 + col;
    Wt[(size_t)dN*C + cK] = f2bf(tile[col][r]);  // Wt[d][c] = g[c]*W[c][d]
  }
}

struct ColArgs {
  const float* W[4]; const float* g[4]; const float* b[4]; const float* extra[4];
  float* ocs[4]; float* obs[4]; int C[4];
};

__global__ __launch_bounds__(256) void prep_colsum(ColArgs a){
  int j = blockIdx.y;
  int C = a.C[j];
  int d0 = blockIdx.x * 64;
  if (d0 >= C) return;
  int dl = threadIdx.x & 63;
  int g  = threadIdx.x >> 6;
  int d  = d0 + dl;
  const float* W = a.W[j]; const float* gv = a.g[j]; const float* bv = a.b[j];
  float cs = 0.f, bs = 0.f;
  for (int c = g; c < C; c += 4){
    float gc = gv[c], bc = bv[c];
    float w = W[(size_t)c*C + d];
    cs += gc*w;
    bs += bc*w;
  }
  __shared__ float rcs[4][64], rbs[4][64];
  rcs[g][dl] = cs; rbs[g][dl] = bs;
  __syncthreads();
  if (threadIdx.x < 64){
    float c0 = rcs[0][dl]+rcs[1][dl]+rcs[2][dl]+rcs[3][dl];
    float b0 = rbs[0][dl]+rbs[1][dl]+rbs[2][dl]+rbs[3][dl];
    if (a.extra[j]) b0 += a.extra[j][d];
    a.ocs[j][d] = c0;
    a.obs[j][d] = b0;
  }
}

// ---------------- fused branch kernel v2 ----------------
// C=128: PX=64 px/block, 512 blocks. C=256: PX=32 px/block, 256 blocks.
// 8 waves (512 thr), wave grid 2(px) x 4(d32). Bs = uniform 32KB [128d][128c] tile.
// LDS 68.6KB -> 2 blocks/CU. Persistent regs ~64/thread -> no spills at 128 cap.
template<int C>
__global__ __launch_bounds__(512, 4) void fusedv2(
    const float* __restrict__ x,
    const unsigned short* __restrict__ WtCur,
    const unsigned short* __restrict__ WtRef,
    const unsigned short* __restrict__ WtConv,
    const float* __restrict__ colC, const float* __restrict__ biasC,
    const float* __restrict__ colR, const float* __restrict__ biasR,
    const float* __restrict__ bns, const float* __restrict__ bnb,
    float* __restrict__ out, int HW){
  constexpr int T = 5;
  constexpr int PX   = (C==128) ? 64 : 32;   // pixels per block
  constexpr int PQn  = PX/4;                  // px quads
  constexpr int NP   = C/128;                 // d-passes of 128
  constexpr int KCH  = C/128;                 // K-chunks of 128
  constexpr int MROWS= PX/2;                  // px rows per wave
  constexpr int MF   = MROWS/16;              // m-fragments per wave
  constexpr int G    = 512/PX;                // stat groups
  constexpr int CH   = C/8;                   // chunks per As row

  __shared__ __align__(16) char Lraw[(size_t)PX*C*4 + 32768];  // As|Hs|Bs = 64KB
  short* As = (short*)Lraw;
  short* Hs = (short*)(Lraw + PX*C*2);
  short* Bs = (short*)(Lraw + PX*C*4);
  float* pool = (float*)Lraw;                 // PX x (C+1) floats = 33KB
  __shared__ float red[1024];
  __shared__ float smean[PX], srstd[PX];

  int px0 = blockIdx.x*PX;
  int b = px0 / HW, hw0 = px0 % HW;
  int tid = threadIdx.x, lane = tid&63, wid = tid>>6;
  int wr = wid>>2, wc = wid&3, hi = lane>>4, cl = lane&15;
  const float* xbase = x + (size_t)b*C*T*HW + hw0;

  // ---- helpers (lambdas keep indices compile-time via unroll) ----
  auto stageX = [&](const float* xb){
    int w = tid>>6, pqs = lane>>4;
    #pragma unroll
    for (int i=0;i<4;++i){
      int c, pq;
      if constexpr (C==128){ c = w*16 + cl; pq = i*4 + pqs; }
      else                 { c = w*32 + (i&1)*16 + cl; pq = (i>>1)*4 + pqs; }
      f32x4 v = *(const f32x4*)(xb + (size_t)c*(T*HW) + pq*4);
      #pragma unroll
      for (int j=0;j<4;++j){
        int px = pq*4 + j;
        *(unsigned short*)((char*)As + px*(2*C) + (((c>>3) ^ (px&7))*16) + (c&7)*2) = f2bf(v[j]);
      }
    }
  };

  auto statsX = [&](){
    int px = tid & (PX-1), g = tid / PX;
    constexpr int PER = CH / G;   // = 2
    float s=0.f, q=0.f;
    #pragma unroll
    for (int k=0;k<PER;++k){
      int ch = g*PER + k;
      short8 v = *(const short8*)((const char*)As + px*(2*C) + ((ch ^ (px&7))*16));
      #pragma unroll
      for (int e=0;e<8;++e){ float f = bf2f((unsigned short)v[e]); s += f; q += f*f; }
    }
    red[g*PX+px] = s; red[512 + g*PX+px] = q;
    __syncthreads();
    if (tid < PX){
      float ss=0.f, qq=0.f;
      #pragma unroll
      for (int gg=0; gg<G; ++gg){ ss += red[gg*PX+tid]; qq += red[512+gg*PX+tid]; }
      float m = ss*(1.f/C);
      float var = fmaxf(qq*(1.f/C) - m*m, 0.f);
      smean[tid] = m;
      srstd[tid] = rsqrtf(var + 1e-5f);
    }
    __syncthreads();
  };

  auto stageW = [&](const unsigned short* Wt, int p, int kc){
    const unsigned short* src = Wt + (size_t)(p*128)*C + kc*128;
    #pragma unroll
    for (int it=0; it<4; ++it){
      int i = tid + it*512, row = i>>4, ch = i&15;
      short8 v = *(const short8*)(src + (size_t)row*C + ch*8);
      *(short8*)((char*)Bs + row*256 + ((ch ^ (row&7))*16)) = v;
    }
  };

  auto mfmaKC = [&](const short* Amat, f32x4 acc[MF][2], int kc){
    int pqs = hi & 3;
    #pragma unroll
    for (int ks=0; ks<4; ++ks){
      short8 af[MF], bfr[2];
      #pragma unroll
      for (int mf=0;mf<MF;++mf){
        int row = wr*MROWS + mf*16 + cl;
        int chunk = (kc*16 + ks*4 + pqs) ^ (row&7);
        af[mf] = *(const short8*)((const char*)Amat + row*(2*C) + chunk*16);
      }
      #pragma unroll
      for (int nf=0;nf<2;++nf){
        int row = wc*32 + nf*16 + cl;
        int chunk = (ks*4 + pqs) ^ (row&7);
        bfr[nf] = *(const short8*)((const char*)Bs + row*256 + chunk*16);
      }
      #pragma unroll
      for (int mf=0;mf<MF;++mf)
        #pragma unroll
        for (int nf=0;nf<2;++nf)
          acc[mf][nf] = __builtin_amdgcn_mfma_f32_16x16x32_bf16(af[mf], bfr[nf], acc[mf][nf], 0,0,0);
    }
  };

  // ---- per-thread persistent state ----
  float csR[NP][2], biR[NP][2], scv[NP][2], sbv[NP][2];
  #pragma unroll
  for (int p=0;p<NP;++p)
    #pragma unroll
    for (int nf=0;nf<2;++nf){
      int d = p*128 + wc*32 + nf*16 + cl;
      csR[p][nf] = colR[d]; biR[p][nf] = biasR[d];
      scv[p][nf] = bns[d];  sbv[p][nf] = bnb[d];
    }
  unsigned short pv[NP][2][MF*4], cv[NP][2][MF*4];
  f32x4 mx[NP][2][MF], sm[NP][2][MF];
  #pragma unroll
  for (int p=0;p<NP;++p)
    #pragma unroll
    for (int nf=0;nf<2;++nf)
      #pragma unroll
      for (int mf=0;mf<MF;++mf){ mx[p][nf][mf] = vsplat(-3.0e38f); sm[p][nf][mf] = vzero(); }

  // ---- phase 0: cur projection -> pv/cv in registers ----
  stageX(xbase + (size_t)(T-1)*HW);
  __syncthreads();
  statsX();
  #pragma unroll
  for (int p=0;p<NP;++p){
    f32x4 acc[MF][2];
    #pragma unroll
    for (int mf=0;mf<MF;++mf){ acc[mf][0]=vzero(); acc[mf][1]=vzero(); }
    #pragma unroll
    for (int kc=0;kc<KCH;++kc){
      __syncthreads();
      stageW(WtCur, p, kc);
      __syncthreads();
      mfmaKC(As, acc, kc);
    }
    #pragma unroll
    for (int nf=0;nf<2;++nf){
      int dg = p*128 + wc*32 + nf*16 + cl;
      float cs = colC[dg], bi = biasC[dg];
      #pragma unroll
      for (int mf=0;mf<MF;++mf)
        #pragma unroll
        for (int r=0;r<4;++r){
          int pl = wr*MROWS + mf*16 + hi*4 + r;
          float P = srstd[pl]*(acc[mf][nf][r] - smean[pl]*cs) + bi;
          pv[p][nf][mf*4+r] = f2bf(P);
          cv[p][nf][mf*4+r] = *(const unsigned short*)((const char*)As + pl*(2*C) + (((dg>>3)^(pl&7))*16) + (dg&7)*2);
        }
    }
  }

  // ---- t loop ----
  for (int t=0;t<4;++t){
    __syncthreads();
    stageX(xbase + (size_t)t*HW);
    __syncthreads();
    statsX();
    // ref GEMM -> h into Hs
    #pragma unroll
    for (int p=0;p<NP;++p){
      f32x4 acc[MF][2];
      #pragma unroll
      for (int mf=0;mf<MF;++mf){ acc[mf][0]=vzero(); acc[mf][1]=vzero(); }
      #pragma unroll
      for (int kc=0;kc<KCH;++kc){
        __syncthreads();
        stageW(WtRef, p, kc);
        __syncthreads();
        mfmaKC(As, acc, kc);
      }
      #pragma unroll
      for (int nf=0;nf<2;++nf){
        int dg = p*128 + wc*32 + nf*16 + cl;
        #pragma unroll
        for (int mf=0;mf<MF;++mf)
          #pragma unroll
          for (int r=0;r<4;++r){
            int pl = wr*MROWS + mf*16 + hi*4 + r;
            float pre = srstd[pl]*(acc[mf][nf][r] - smean[pl]*csR[p][nf]) + biR[p][nf]
                      + bf2f(pv[p][nf][mf*4+r]);
            float hv = bf2f(cv[p][nf][mf*4+r]) + siluf(pre);
            *(unsigned short*)((char*)Hs + pl*(2*C) + (((dg>>3)^(pl&7))*16) + (dg&7)*2) = f2bf(hv);
          }
      }
    }
    // conv GEMM -> pool accumulate
    #pragma unroll
    for (int p=0;p<NP;++p){
      f32x4 acc[MF][2];
      #pragma unroll
      for (int mf=0;mf<MF;++mf){ acc[mf][0]=vzero(); acc[mf][1]=vzero(); }
      #pragma unroll
      for (int kc=0;kc<KCH;++kc){
        __syncthreads();
        stageW(WtConv, p, kc);
        __syncthreads();
        mfmaKC(Hs, acc, kc);
      }
      #pragma unroll
      for (int nf=0;nf<2;++nf){
        #pragma unroll
        for (int mf=0;mf<MF;++mf)
          #pragma unroll
          for (int r=0;r<4;++r){
            float y = siluf(acc[mf][nf][r]*scv[p][nf] + sbv[p][nf]);
            mx[p][nf][mf][r] = fmaxf(mx[p][nf][mf][r], y);
            sm[p][nf][mf][r] += y;
          }
      }
    }
  }

  // ---- pool -> LDS -> coalesced transposed store ----
  __syncthreads();
  #pragma unroll
  for (int p=0;p<NP;++p)
    #pragma unroll
    for (int nf=0;nf<2;++nf){
      int dl = p*128 + wc*32 + nf*16 + cl;
      #pragma unroll
      for (int mf=0;mf<MF;++mf)
        #pragma unroll
        for (int r=0;r<4;++r){
          int pl = wr*MROWS + mf*16 + hi*4 + r;
          pool[pl*(C+1) + dl] = mx[p][nf][mf][r] + 0.25f*sm[p][nf][mf][r];
        }
    }
  __syncthreads();
  #pragma unroll
  for (int it=0; it<4; ++it){
    int i = tid + it*512;
    int dl = i / PQn;
    int pq = i % PQn;
    f32x4 vv;
    #pragma unroll
    for (int k=0;k<4;++k) vv[k] = pool[(pq*4+k)*(C+1) + dl];
    *(f32x4*)(out + (size_t)(b*C + dl)*HW + hw0 + pq*4) = vv;
  }
}

// ---------------- host ----------------
extern "C" void kernel_launch(void* const* d_in, const int* in_sizes, int n_in,
                              void* d_out, int out_size, void* d_ws, size_t ws_size,
                              hipStream_t stream) {
  (void)in_sizes; (void)n_in; (void)out_size; (void)ws_size;
  const float* x2    = (const float*)d_in[0];
  const float* x1    = (const float*)d_in[1];
  const float* g2c   = (const float*)d_in[3];
  const float* b2c   = (const float*)d_in[4];
  const float* g2r   = (const float*)d_in[5];
  const float* b2r   = (const float*)d_in[6];
  const float* W2cur = (const float*)d_in[7];
  const float* W2ref = (const float*)d_in[8];
  const float* bias2 = (const float*)d_in[9];
  const float* convw2= (const float*)d_in[10];
  const float* bns2  = (const float*)d_in[11];
  const float* bnb2  = (const float*)d_in[12];
  const float* g1c   = (const float*)d_in[13];
  const float* b1c   = (const float*)d_in[14];
  const float* g1r   = (const float*)d_in[15];
  const float* b1r   = (const float*)d_in[16];
  const float* W1cur = (const float*)d_in[17];
  const float* W1ref = (const float*)d_in[18];
  const float* bias1 = (const float*)d_in[19];
  const float* convw1= (const float*)d_in[20];
  const float* bns1  = (const float*)d_in[21];
  const float* bnb1  = (const float*)d_in[22];

  const int C2 = 128, C1 = 256;
  const int NP2 = 8*64*64, NP1 = 8*32*32;
  const int HW2 = 4096, HW1 = 1024;

  char* ws = (char*)d_ws;
  size_t off = 0;
  auto alloc = [&](size_t bytes){ size_t o = off; off = (off + bytes + 255) & ~(size_t)255; return o; };
  size_t oWtC2 = alloc((size_t)C2*C2*2), oWtR2 = alloc((size_t)C2*C2*2), oWtV2 = alloc((size_t)C2*C2*2);
  size_t oWtC1 = alloc((size_t)C1*C1*2), oWtR1 = alloc((size_t)C1*C1*2), oWtV1 = alloc((size_t)C1*C1*2);
  size_t oColC2 = alloc(C2*4), oBiasC2 = alloc(C2*4), oColR2 = alloc(C2*4), oBiasR2 = alloc(C2*4);
  size_t oColC1 = alloc(C1*4), oBiasC1 = alloc(C1*4), oColR1 = alloc(C1*4), oBiasR1 = alloc(C1*4);

  unsigned short* WtC2 = (unsigned short*)(ws + oWtC2);
  unsigned short* WtR2 = (unsigned short*)(ws + oWtR2);
  unsigned short* WtV2 = (unsigned short*)(ws + oWtV2);
  unsigned short* WtC1 = (unsigned short*)(ws + oWtC1);
  unsigned short* WtR1 = (unsigned short*)(ws + oWtR1);
  unsigned short* WtV1 = (unsigned short*)(ws + oWtV1);
  float* ColC2 = (float*)(ws + oColC2); float* BiasC2 = (float*)(ws + oBiasC2);
  float* ColR2 = (float*)(ws + oColR2); float* BiasR2 = (float*)(ws + oBiasR2);
  float* ColC1 = (float*)(ws + oColC1); float* BiasC1 = (float*)(ws + oBiasC1);
  float* ColR1 = (float*)(ws + oColR1); float* BiasR1 = (float*)(ws + oBiasR1);

  PrepArgs pa;
  pa.W[0]=W2cur;  pa.g[0]=g2c;     pa.Wt[0]=WtC2; pa.C[0]=C2;
  pa.W[1]=W2ref;  pa.g[1]=g2r;     pa.Wt[1]=WtR2; pa.C[1]=C2;
  pa.W[2]=convw2; pa.g[2]=nullptr; pa.Wt[2]=WtV2; pa.C[2]=C2;
  pa.W[3]=W1cur;  pa.g[3]=g1c;     pa.Wt[3]=WtC1; pa.C[3]=C1;
  pa.W[4]=W1ref;  pa.g[4]=g1r;     pa.Wt[4]=WtR1; pa.C[4]=C1;
  pa.W[5]=convw1; pa.g[5]=nullptr; pa.Wt[5]=WtV1; pa.C[5]=C1;
  prep_transpose<<<dim3(8,8,6), 256, 0, stream>>>(pa);

  ColArgs ca;
  ca.W[0]=W2cur; ca.g[0]=g2c; ca.b[0]=b2c; ca.extra[0]=nullptr; ca.ocs[0]=ColC2; ca.obs[0]=BiasC2; ca.C[0]=C2;
  ca.W[1]=W2ref; ca.g[1]=g2r; ca.b[1]=b2r; ca.extra[1]=bias2;   ca.ocs[1]=ColR2; ca.obs[1]=BiasR2; ca.C[1]=C2;
  ca.W[2]=W1cur; ca.g[2]=g1c; ca.b[2]=b1c; ca.extra[2]=nullptr; ca.ocs[2]=ColC1; ca.obs[2]=BiasC1; ca.C[2]=C1;
  ca.W[3]=W1ref; ca.g[3]=g1r; ca.b[3]=b1r; ca.extra[3]=bias1;   ca.ocs[3]=ColR1; ca.obs[3]=BiasR1; ca.C[3]=C1;
  prep_colsum<<<dim3(4, 4), 256, 0, stream>>>(ca);

  float* out2 = (float*)d_out;
  float* out1 = out2 + (size_t)8*C2*HW2;

  fusedv2<128><<<NP2/64, 512, 0, stream>>>(
      x2, WtC2, WtR2, WtV2, ColC2, BiasC2, ColR2, BiasR2, bns2, bnb2, out2, HW2);
  fusedv2<256><<<NP1/32, 512, 0, stream>>>(
      x1, WtC1, WtR1, WtV1, ColC1, BiasC1, ColR1, BiasR1, bns1, bnb1, out1, HW1);
}

// Round 7
// 144.273 us; speedup vs baseline: 3.7760x; 2.3929x over previous
//
#include <hip/hip_runtime.h>
#include <stdint.h>

#define DI __device__ __forceinline__

typedef __attribute__((ext_vector_type(8))) short short8;
typedef __attribute__((ext_vector_type(4))) float f32x4;

DI float bf2f(unsigned short u){ union{unsigned int i; float f;} v; v.i = ((unsigned int)u)<<16; return v.f; }
DI unsigned short f2bf(float f){ union{float f; unsigned int i;} v; v.f=f; return (unsigned short)((v.i + 0x7fffu + ((v.i>>16)&1u))>>16); }
DI float siluf(float x){ return x/(1.f + __expf(-x)); }
DI f32x4 vzero(){ f32x4 z; z[0]=0.f;z[1]=0.f;z[2]=0.f;z[3]=0.f; return z; }
DI f32x4 vsplat(float x){ f32x4 z; z[0]=x;z[1]=x;z[2]=x;z[3]=x; return z; }

// ---------------- weight prep ----------------
struct PrepArgs {
  const float* W[6];
  const float* g[6];
  unsigned short* Wt[6];
  int C[6];
};

__global__ __launch_bounds__(256) void prep_transpose(PrepArgs a){
  int m = blockIdx.z;
  int C = a.C[m];
  int nt = C >> 5;
  if ((int)blockIdx.x >= nt || (int)blockIdx.y >= nt) return;
  __shared__ float tile[32][33];
  int col = threadIdx.x & 31;
  int rr  = threadIdx.x >> 5;
  const float* W = a.W[m];
  const float* g = a.g[m];
  #pragma unroll
  for (int p=0;p<4;++p){
    int r = rr + p*8;
    int cK = blockIdx.x*32 + r;
    int dN = blockIdx.y*32 + col;
    float v = W[(size_t)cK*C + dN];
    if (g) v *= g[cK];
    tile[r][col] = v;
  }
  __syncthreads();
  unsigned short* Wt = a.Wt[m];
  #pragma unroll
  for (int p=0;p<4;++p){
    int r = rr + p*8;
    int dN = blockIdx.y*32 + r;
    int cK = blockIdx.x*32 + col;
    Wt[(size_t)dN*C + cK] = f2bf(tile[col][r]);  // Wt[d][c] = g[c]*W[c][d]
  }
}

struct ColArgs {
  const float* W[4]; const float* g[4]; const float* b[4]; const float* extra[4];
  float* ocs[4]; float* obs[4]; int C[4];
};

__global__ __launch_bounds__(256) void prep_colsum(ColArgs a){
  int j = blockIdx.y;
  int C = a.C[j];
  int d0 = blockIdx.x * 64;
  if (d0 >= C) return;
  int dl = threadIdx.x & 63;
  int g  = threadIdx.x >> 6;
  int d  = d0 + dl;
  const float* W = a.W[j]; const float* gv = a.g[j]; const float* bv = a.b[j];
  float cs = 0.f, bs = 0.f;
  for (int c = g; c < C; c += 4){
    float gc = gv[c], bc = bv[c];
    float w = W[(size_t)c*C + d];
    cs += gc*w;
    bs += bc*w;
  }
  __shared__ float rcs[4][64], rbs[4][64];
  rcs[g][dl] = cs; rbs[g][dl] = bs;
  __syncthreads();
  if (threadIdx.x < 64){
    float c0 = rcs[0][dl]+rcs[1][dl]+rcs[2][dl]+rcs[3][dl];
    float b0 = rbs[0][dl]+rbs[1][dl]+rbs[2][dl]+rbs[3][dl];
    if (a.extra[j]) b0 += a.extra[j][d];
    a.ocs[j][d] = c0;
    a.obs[j][d] = b0;
  }
}

// ---------------- fused branch kernel v3 ----------------
// C=128: PX=64 px/block (512 blocks), waves 2(px)x4(d).  C=256: PX=16 (512 blocks), waves 1x8.
// Single As buffer reused cur -> ref_t -> h_t; P/cur fragments live in registers.
// Bs K-chunked [C rows][64 c].  No launch_bounds occupancy arg (R6 lesson: forced 64-reg cap = spills).
template<int C, int PX>
__global__ __launch_bounds__(512) void fusedv3(
    const float* __restrict__ x,
    const unsigned short* __restrict__ WtCur,
    const unsigned short* __restrict__ WtRef,
    const unsigned short* __restrict__ WtConv,
    const float* __restrict__ colC, const float* __restrict__ biasC,
    const float* __restrict__ colR, const float* __restrict__ biasR,
    const float* __restrict__ bns, const float* __restrict__ bnb,
    float* __restrict__ out, int HW){
  constexpr int T = 5;
  constexpr int WCN = C/32;          // d-wave groups (4 or 8)
  constexpr int MROWS = PX/(8/WCN);  // px rows per wave (32 or 16)
  constexpr int MF = MROWS/16;       // m fragments (2 or 1)
  constexpr int KC = C/64;           // 64-wide K chunks
  constexpr int G = 512/PX;          // LN stat groups
  constexpr int PER = (C/8)/G;       // b128 chunks per thread in stats
  constexpr int ABYTES = PX*C*2;
  constexpr int BBYTES = C*128;      // [C][64] bf16
  constexpr int LDS_TOT = ABYTES + BBYTES + 4096 + 2*PX*4;
  static_assert(PX*(C+1)*4 <= ABYTES + BBYTES + 4096, "pool fits");

  __shared__ __align__(16) char L[LDS_TOT];
  char* Bsb = L + ABYTES;
  float* red = (float*)(L + ABYTES + BBYTES);
  float* smean = (float*)(L + ABYTES + BBYTES + 4096);
  float* srstd = smean + PX;

  int px0 = blockIdx.x*PX;
  int b = px0 / HW, hw0 = px0 % HW;
  int tid = threadIdx.x, lane = tid&63, wid = tid>>6;
  int wc = wid % WCN, wr = wid / WCN;
  int cl = lane&15, hi = lane>>4;
  const float* xbase = x + (size_t)b*C*T*HW + hw0;

  auto stageXf = [&](const float* xb){
    #pragma unroll
    for (int i=0;i<(C*PX/2048);++i){
      int c, pq;
      if constexpr (C==128){ c = wid*16 + cl; pq = i*4 + hi; }
      else                 { c = wid*32 + i*16 + cl; pq = hi; }
      f32x4 v = *(const f32x4*)(xb + (size_t)c*(T*HW) + pq*4);
      #pragma unroll
      for (int j=0;j<4;++j){
        int px = pq*4 + j;
        *(unsigned short*)(L + px*(2*C) + (((c>>3) ^ (px&7))*16) + (c&7)*2) = f2bf(v[j]);
      }
    }
  };

  auto statsXf = [&](){
    int px = tid & (PX-1), g = tid / PX;
    float s=0.f, q=0.f;
    #pragma unroll
    for (int k2=0;k2<PER;++k2){
      int ch = g*PER + k2;
      short8 v = *(const short8*)(L + px*(2*C) + ((ch ^ (px&7))*16));
      #pragma unroll
      for (int e=0;e<8;++e){ float f = bf2f((unsigned short)v[e]); s += f; q += f*f; }
    }
    red[g*PX+px] = s; red[512 + g*PX+px] = q;
    __syncthreads();
    if (tid < PX){
      float ss=0.f, qq=0.f;
      #pragma unroll
      for (int gg=0; gg<G; ++gg){ ss += red[gg*PX+tid]; qq += red[512+gg*PX+tid]; }
      float m = ss*(1.f/C);
      float var = fmaxf(qq*(1.f/C) - m*m, 0.f);
      smean[tid] = m;
      srstd[tid] = rsqrtf(var + 1e-5f);
    }
    __syncthreads();
  };

  auto stageWf = [&](const unsigned short* Wt, int kc){
    #pragma unroll
    for (int it=0; it<C/64; ++it){
      int i = tid + it*512, row = i>>3, ch = i&7;
      short8 v = *(const short8*)(Wt + (size_t)row*C + kc*64 + ch*8);
      *(short8*)(Bsb + row*128 + ((ch ^ (row&7))*16)) = v;
    }
  };

  auto gemmKCf = [&](f32x4 (&acc)[MF][2], int kc){
    #pragma unroll
    for (int ks=0;ks<2;++ks){
      short8 af[MF], bf8[2];
      #pragma unroll
      for (int mf=0;mf<MF;++mf){
        int row = wr*MROWS + mf*16 + cl;
        int chs = kc*8 + ((ks*4 + hi) ^ (row&7));
        af[mf] = *(const short8*)(L + row*(2*C) + chs*16);
      }
      #pragma unroll
      for (int nf=0;nf<2;++nf){
        int row = wc*32 + nf*16 + cl;
        int chs = (ks*4 + hi) ^ (row&7);
        bf8[nf] = *(const short8*)(Bsb + row*128 + chs*16);
      }
      #pragma unroll
      for (int mf=0;mf<MF;++mf)
        #pragma unroll
        for (int nf=0;nf<2;++nf)
          acc[mf][nf] = __builtin_amdgcn_mfma_f32_16x16x32_bf16(af[mf], bf8[nf], acc[mf][nf], 0,0,0);
    }
  };

  // per-thread persistent state (small: <=64 regs)
  float csR[2], biR[2], scn[2], sbn[2];
  #pragma unroll
  for (int nf=0;nf<2;++nf){
    int d = wc*32 + nf*16 + cl;
    csR[nf] = colR[d]; biR[nf] = biasR[d];
    scn[nf] = bns[d];  sbn[nf] = bnb[d];
  }
  unsigned short pv[2][MF*4], cvr[2][MF*4];
  f32x4 mx[2][MF], sm[2][MF];
  #pragma unroll
  for (int nf=0;nf<2;++nf)
    #pragma unroll
    for (int mf=0;mf<MF;++mf){ mx[nf][mf] = vsplat(-3.0e38f); sm[nf][mf] = vzero(); }

  // ---- phase 0: cur projection -> pv (P) and cvr (raw cur) in registers ----
  stageXf(xbase + (size_t)(T-1)*HW);
  __syncthreads();
  statsXf();
  {
    f32x4 acc[MF][2];
    #pragma unroll
    for (int mf=0;mf<MF;++mf){ acc[mf][0]=vzero(); acc[mf][1]=vzero(); }
    #pragma unroll
    for (int kc=0;kc<KC;++kc){
      stageWf(WtCur, kc);
      __syncthreads();
      gemmKCf(acc, kc);
      __syncthreads();
    }
    #pragma unroll
    for (int nf=0;nf<2;++nf){
      int dg = wc*32 + nf*16 + cl;
      float cs = colC[dg], bi = biasC[dg];
      #pragma unroll
      for (int mf=0;mf<MF;++mf)
        #pragma unroll
        for (int r=0;r<4;++r){
          int pl = wr*MROWS + mf*16 + hi*4 + r;
          float P = srstd[pl]*(acc[mf][nf][r] - smean[pl]*cs) + bi;
          pv[nf][mf*4+r] = f2bf(P);
          cvr[nf][mf*4+r] = *(const unsigned short*)(L + pl*(2*C) + (((dg>>3)^(pl&7))*16) + (dg&7)*2);
        }
    }
  }

  // ---- t loop: ref GEMM -> h (overwrites As) -> conv GEMM -> pool in regs ----
  for (int t=0;t<4;++t){
    __syncthreads();                 // cv/As reads done; As free for next slice
    stageXf(xbase + (size_t)t*HW);
    __syncthreads();
    statsXf();

    f32x4 acc[MF][2];
    #pragma unroll
    for (int mf=0;mf<MF;++mf){ acc[mf][0]=vzero(); acc[mf][1]=vzero(); }
    #pragma unroll
    for (int kc=0;kc<KC;++kc){
      stageWf(WtRef, kc);
      __syncthreads();
      gemmKCf(acc, kc);
      __syncthreads();
    }
    // h epilogue: h = cur + silu(P + refproj + bias); write over As (x_ref dead)
    #pragma unroll
    for (int nf=0;nf<2;++nf){
      int dg = wc*32 + nf*16 + cl;
      #pragma unroll
      for (int mf=0;mf<MF;++mf)
        #pragma unroll
        for (int r=0;r<4;++r){
          int pl = wr*MROWS + mf*16 + hi*4 + r;
          float pre = srstd[pl]*(acc[mf][nf][r] - smean[pl]*csR[nf]) + biR[nf] + bf2f(pv[nf][mf*4+r]);
          float hv = bf2f(cvr[nf][mf*4+r]) + siluf(pre);
          *(unsigned short*)(L + pl*(2*C) + (((dg>>3)^(pl&7))*16) + (dg&7)*2) = f2bf(hv);
        }
    }
    // conv GEMM on h
    f32x4 acc2[MF][2];
    #pragma unroll
    for (int mf=0;mf<MF;++mf){ acc2[mf][0]=vzero(); acc2[mf][1]=vzero(); }
    #pragma unroll
    for (int kc=0;kc<KC;++kc){
      stageWf(WtConv, kc);
      __syncthreads();               // h writes + Bs staging complete
      gemmKCf(acc2, kc);
      __syncthreads();
    }
    #pragma unroll
    for (int nf=0;nf<2;++nf)
      #pragma unroll
      for (int mf=0;mf<MF;++mf)
        #pragma unroll
        for (int r=0;r<4;++r){
          float y = siluf(acc2[mf][nf][r]*scn[nf] + sbn[nf]);
          mx[nf][mf][r] = fmaxf(mx[nf][mf][r], y);
          sm[nf][mf][r] += y;
        }
  }

  // ---- pool -> LDS (stride C+1) -> coalesced transposed store ----
  __syncthreads();
  float* pool = (float*)L;
  #pragma unroll
  for (int nf=0;nf<2;++nf){
    int dl = wc*32 + nf*16 + cl;
    #pragma unroll
    for (int mf=0;mf<MF;++mf)
      #pragma unroll
      for (int r=0;r<4;++r){
        int pl = wr*MROWS + mf*16 + hi*4 + r;
        pool[pl*(C+1) + dl] = mx[nf][mf][r] + 0.25f*sm[nf][mf][r];
      }
  }
  __syncthreads();
  constexpr int PQn = PX/4;
  #pragma unroll
  for (int it=0; it<(C*PQn/512); ++it){
    int i = tid + it*512;
    int dl = i / PQn, pq = i % PQn;
    f32x4 vv;
    #pragma unroll
    for (int k=0;k<4;++k) vv[k] = pool[(pq*4+k)*(C+1) + dl];
    *(f32x4*)(out + (size_t)(b*C + dl)*HW + hw0 + pq*4) = vv;
  }
}

// ---------------- host ----------------
extern "C" void kernel_launch(void* const* d_in, const int* in_sizes, int n_in,
                              void* d_out, int out_size, void* d_ws, size_t ws_size,
                              hipStream_t stream) {
  (void)in_sizes; (void)n_in; (void)out_size; (void)ws_size;
  const float* x2    = (const float*)d_in[0];
  const float* x1    = (const float*)d_in[1];
  const float* g2c   = (const float*)d_in[3];
  const float* b2c   = (const float*)d_in[4];
  const float* g2r   = (const float*)d_in[5];
  const float* b2r   = (const float*)d_in[6];
  const float* W2cur = (const float*)d_in[7];
  const float* W2ref = (const float*)d_in[8];
  const float* bias2 = (const float*)d_in[9];
  const float* convw2= (const float*)d_in[10];
  const float* bns2  = (const float*)d_in[11];
  const float* bnb2  = (const float*)d_in[12];
  const float* g1c   = (const float*)d_in[13];
  const float* b1c   = (const float*)d_in[14];
  const float* g1r   = (const float*)d_in[15];
  const float* b1r   = (const float*)d_in[16];
  const float* W1cur = (const float*)d_in[17];
  const float* W1ref = (const float*)d_in[18];
  const float* bias1 = (const float*)d_in[19];
  const float* convw1= (const float*)d_in[20];
  const float* bns1  = (const float*)d_in[21];
  const float* bnb1  = (const float*)d_in[22];

  const int C2 = 128, C1 = 256;
  const int NP2 = 8*64*64, NP1 = 8*32*32;
  const int HW2 = 4096, HW1 = 1024;

  char* ws = (char*)d_ws;
  size_t off = 0;
  auto alloc = [&](size_t bytes){ size_t o = off; off = (off + bytes + 255) & ~(size_t)255; return o; };
  size_t oWtC2 = alloc((size_t)C2*C2*2), oWtR2 = alloc((size_t)C2*C2*2), oWtV2 = alloc((size_t)C2*C2*2);
  size_t oWtC1 = alloc((size_t)C1*C1*2), oWtR1 = alloc((size_t)C1*C1*2), oWtV1 = alloc((size_t)C1*C1*2);
  size_t oColC2 = alloc(C2*4), oBiasC2 = alloc(C2*4), oColR2 = alloc(C2*4), oBiasR2 = alloc(C2*4);
  size_t oColC1 = alloc(C1*4), oBiasC1 = alloc(C1*4), oColR1 = alloc(C1*4), oBiasR1 = alloc(C1*4);

  unsigned short* WtC2 = (unsigned short*)(ws + oWtC2);
  unsigned short* WtR2 = (unsigned short*)(ws + oWtR2);
  unsigned short* WtV2 = (unsigned short*)(ws + oWtV2);
  unsigned short* WtC1 = (unsigned short*)(ws + oWtC1);
  unsigned short* WtR1 = (unsigned short*)(ws + oWtR1);
  unsigned short* WtV1 = (unsigned short*)(ws + oWtV1);
  float* ColC2 = (float*)(ws + oColC2); float* BiasC2 = (float*)(ws + oBiasC2);
  float* ColR2 = (float*)(ws + oColR2); float* BiasR2 = (float*)(ws + oBiasR2);
  float* ColC1 = (float*)(ws + oColC1); float* BiasC1 = (float*)(ws + oBiasC1);
  float* ColR1 = (float*)(ws + oColR1); float* BiasR1 = (float*)(ws + oBiasR1);

  PrepArgs pa;
  pa.W[0]=W2cur;  pa.g[0]=g2c;     pa.Wt[0]=WtC2; pa.C[0]=C2;
  pa.W[1]=W2ref;  pa.g[1]=g2r;     pa.Wt[1]=WtR2; pa.C[1]=C2;
  pa.W[2]=convw2; pa.g[2]=nullptr; pa.Wt[2]=WtV2; pa.C[2]=C2;
  pa.W[3]=W1cur;  pa.g[3]=g1c;     pa.Wt[3]=WtC1; pa.C[3]=C1;
  pa.W[4]=W1ref;  pa.g[4]=g1r;     pa.Wt[4]=WtR1; pa.C[4]=C1;
  pa.W[5]=convw1; pa.g[5]=nullptr; pa.Wt[5]=WtV1; pa.C[5]=C1;
  prep_transpose<<<dim3(8,8,6), 256, 0, stream>>>(pa);

  ColArgs ca;
  ca.W[0]=W2cur; ca.g[0]=g2c; ca.b[0]=b2c; ca.extra[0]=nullptr; ca.ocs[0]=ColC2; ca.obs[0]=BiasC2; ca.C[0]=C2;
  ca.W[1]=W2ref; ca.g[1]=g2r; ca.b[1]=b2r; ca.extra[1]=bias2;   ca.ocs[1]=ColR2; ca.obs[1]=BiasR2; ca.C[1]=C2;
  ca.W[2]=W1cur; ca.g[2]=g1c; ca.b[2]=b1c; ca.extra[2]=nullptr; ca.ocs[2]=ColC1; ca.obs[2]=BiasC1; ca.C[2]=C1;
  ca.W[3]=W1ref; ca.g[3]=g1r; ca.b[3]=b1r; ca.extra[3]=bias1;   ca.ocs[3]=ColR1; ca.obs[3]=BiasR1; ca.C[3]=C1;
  prep_colsum<<<dim3(4, 4), 256, 0, stream>>>(ca);

  float* out2 = (float*)d_out;
  float* out1 = out2 + (size_t)8*C2*HW2;

  fusedv3<128,64><<<NP2/64, 512, 0, stream>>>(
      x2, WtC2, WtR2, WtV2, ColC2, BiasC2, ColR2, BiasR2, bns2, bnb2, out2, HW2);
  fusedv3<256,16><<<NP1/16, 512, 0, stream>>>(
      x1, WtC1, WtR1, WtV1, ColC1, BiasC1, ColR1, BiasR1, bns1, bnb1, out1, HW1);
}